// Round 2
// baseline (56.276 us; speedup 1.0000x reference)
//
#include <hip/hip_runtime.h>
#include <math.h>

constexpr int BATCH = 32;
constexpr int HW    = 512 * 512;
constexpr int BPB   = 64;            // blocks per batch
constexpr int TPB   = 256;
constexpr int CHUNK = HW / BPB;      // 4096 elements per block
constexpr int ITERS = CHUNK / (TPB * 4);  // 4 float4 iterations per thread
constexpr float EPS = 1e-6f;

__device__ __forceinline__ float wave_reduce(float v) {
#pragma unroll
    for (int off = 32; off > 0; off >>= 1) v += __shfl_down(v, off, 64);
    return v;
}

// ws layout: region r in [0,5): ws[r*BATCH*BPB + b*BPB + blk]
// r0 = mask count partials, r1 = sum(pred*m), r2 = sum(gt*m),
// r3 = sum(|pred-shp|*m), r4 = sum(|gt-shg|*m)

__global__ __launch_bounds__(TPB) void pass1_sums(const float* __restrict__ pred,
                                                  const float* __restrict__ gt,
                                                  const int* __restrict__ mask,
                                                  float* __restrict__ ws) {
    const int b = blockIdx.y, blk = blockIdx.x;
    const size_t base = (size_t)b * HW + (size_t)blk * CHUNK;
    float c = 0.f, sp = 0.f, sg = 0.f;
#pragma unroll
    for (int it = 0; it < ITERS; ++it) {
        const int idx = (it * TPB + (int)threadIdx.x) * 4;
        const float4 p = *(const float4*)(pred + base + idx);
        const float4 g = *(const float4*)(gt   + base + idx);
        const int4   m = *(const int4*)(mask  + base + idx);
        const float m0 = m.x ? 1.f : 0.f, m1 = m.y ? 1.f : 0.f;
        const float m2 = m.z ? 1.f : 0.f, m3 = m.w ? 1.f : 0.f;
        c  += m0 + m1 + m2 + m3;
        sp += p.x * m0 + p.y * m1 + p.z * m2 + p.w * m3;
        sg += g.x * m0 + g.y * m1 + g.z * m2 + g.w * m3;
    }
    __shared__ float sd[3][TPB / 64];
    c = wave_reduce(c); sp = wave_reduce(sp); sg = wave_reduce(sg);
    const int lane = threadIdx.x & 63, wid = threadIdx.x >> 6;
    if (lane == 0) { sd[0][wid] = c; sd[1][wid] = sp; sd[2][wid] = sg; }
    __syncthreads();
    if (threadIdx.x == 0) {
        float tc = 0.f, tp = 0.f, tg = 0.f;
#pragma unroll
        for (int i = 0; i < TPB / 64; ++i) { tc += sd[0][i]; tp += sd[1][i]; tg += sd[2][i]; }
        const int o = b * BPB + blk;
        ws[0 * BATCH * BPB + o] = tc;
        ws[1 * BATCH * BPB + o] = tp;
        ws[2 * BATCH * BPB + o] = tg;
    }
}

__global__ __launch_bounds__(TPB) void pass2_absums(const float* __restrict__ pred,
                                                    const float* __restrict__ gt,
                                                    const int* __restrict__ mask,
                                                    float* __restrict__ ws) {
    const int b = blockIdx.y, blk = blockIdx.x;
    __shared__ float tot[3];
    if (threadIdx.x < 64) {
        float v0 = ws[0 * BATCH * BPB + b * BPB + threadIdx.x];
        float v1 = ws[1 * BATCH * BPB + b * BPB + threadIdx.x];
        float v2 = ws[2 * BATCH * BPB + b * BPB + threadIdx.x];
        v0 = wave_reduce(v0); v1 = wave_reduce(v1); v2 = wave_reduce(v2);
        if (threadIdx.x == 0) { tot[0] = v0; tot[1] = v1; tot[2] = v2; }
    }
    __syncthreads();
    const float count = fmaxf(tot[0], 1.0f);
    const float shp = tot[1] / count, shg = tot[2] / count;

    const size_t base = (size_t)b * HW + (size_t)blk * CHUNK;
    float ap = 0.f, ag = 0.f;
#pragma unroll
    for (int it = 0; it < ITERS; ++it) {
        const int idx = (it * TPB + (int)threadIdx.x) * 4;
        const float4 p = *(const float4*)(pred + base + idx);
        const float4 g = *(const float4*)(gt   + base + idx);
        const int4   m = *(const int4*)(mask  + base + idx);
        const float m0 = m.x ? 1.f : 0.f, m1 = m.y ? 1.f : 0.f;
        const float m2 = m.z ? 1.f : 0.f, m3 = m.w ? 1.f : 0.f;
        ap += fabsf(p.x - shp) * m0 + fabsf(p.y - shp) * m1
            + fabsf(p.z - shp) * m2 + fabsf(p.w - shp) * m3;
        ag += fabsf(g.x - shg) * m0 + fabsf(g.y - shg) * m1
            + fabsf(g.z - shg) * m2 + fabsf(g.w - shg) * m3;
    }
    __shared__ float sd[2][TPB / 64];
    ap = wave_reduce(ap); ag = wave_reduce(ag);
    const int lane = threadIdx.x & 63, wid = threadIdx.x >> 6;
    if (lane == 0) { sd[0][wid] = ap; sd[1][wid] = ag; }
    __syncthreads();
    if (threadIdx.x == 0) {
        float ta = 0.f, tb = 0.f;
#pragma unroll
        for (int i = 0; i < TPB / 64; ++i) { ta += sd[0][i]; tb += sd[1][i]; }
        const int o = b * BPB + blk;
        ws[3 * BATCH * BPB + o] = ta;
        ws[4 * BATCH * BPB + o] = tb;
    }
}

__global__ __launch_bounds__(TPB) void pass3_out(const float* __restrict__ pred,
                                                 const float* __restrict__ gt,
                                                 const int* __restrict__ mask,
                                                 const float* __restrict__ ws,
                                                 float* __restrict__ out) {
    const int b = blockIdx.y, blk = blockIdx.x;
    __shared__ float tot[5];
    if (threadIdx.x < 64) {
        float v0 = ws[0 * BATCH * BPB + b * BPB + threadIdx.x];
        float v1 = ws[1 * BATCH * BPB + b * BPB + threadIdx.x];
        float v2 = ws[2 * BATCH * BPB + b * BPB + threadIdx.x];
        float v3 = ws[3 * BATCH * BPB + b * BPB + threadIdx.x];
        float v4 = ws[4 * BATCH * BPB + b * BPB + threadIdx.x];
        v0 = wave_reduce(v0); v1 = wave_reduce(v1); v2 = wave_reduce(v2);
        v3 = wave_reduce(v3); v4 = wave_reduce(v4);
        if (threadIdx.x == 0) { tot[0]=v0; tot[1]=v1; tot[2]=v2; tot[3]=v3; tot[4]=v4; }
    }
    __syncthreads();
    const float count = fmaxf(tot[0], 1.0f);
    const float shp = tot[1] / count, shg = tot[2] / count;
    const float iscp = 1.0f / fmaxf(tot[3] / count, EPS);
    const float iscg = 1.0f / fmaxf(tot[4] / count, EPS);

    const size_t base = (size_t)b * HW + (size_t)blk * CHUNK;
#pragma unroll
    for (int it = 0; it < ITERS; ++it) {
        const int idx = (it * TPB + (int)threadIdx.x) * 4;
        const float4 p = *(const float4*)(pred + base + idx);
        const float4 g = *(const float4*)(gt   + base + idx);
        const int4   m = *(const int4*)(mask  + base + idx);
        float4 o;
        o.x = m.x ? fabsf((p.x - shp) * iscp - (g.x - shg) * iscg) : 0.f;
        o.y = m.y ? fabsf((p.y - shp) * iscp - (g.y - shg) * iscg) : 0.f;
        o.z = m.z ? fabsf((p.z - shp) * iscp - (g.z - shg) * iscg) : 0.f;
        o.w = m.w ? fabsf((p.w - shp) * iscp - (g.w - shg) * iscg) : 0.f;
        *(float4*)(out + base + idx) = o;
    }
}

extern "C" void kernel_launch(void* const* d_in, const int* in_sizes, int n_in,
                              void* d_out, int out_size, void* d_ws, size_t ws_size,
                              hipStream_t stream) {
    const float* pred = (const float*)d_in[0];
    const float* gt   = (const float*)d_in[1];
    const int*   mask = (const int*)d_in[2];
    float* out = (float*)d_out;
    float* ws  = (float*)d_ws;

    dim3 grid(BPB, BATCH), block(TPB);
    pass1_sums <<<grid, block, 0, stream>>>(pred, gt, mask, ws);
    pass2_absums<<<grid, block, 0, stream>>>(pred, gt, mask, ws);
    pass3_out  <<<grid, block, 0, stream>>>(pred, gt, mask, ws, out);
}